// Round 1
// baseline (737.322 us; speedup 1.0000x reference)
//
#include <hip/hip_runtime.h>

typedef unsigned short u16;
typedef __attribute__((ext_vector_type(8))) short bf16x8;
typedef __attribute__((ext_vector_type(4))) float f32x4;

__device__ __forceinline__ unsigned f2bf(float f) {
  unsigned u = __float_as_uint(f);
  return (u + 0x7fffu + ((u >> 16) & 1u)) >> 16;  // RNE fp32 -> bf16 bits
}

// ---------------------------------------------------------------------------
// Tiled MFMA GEMM:  C[b] (BMxBN tile grid) = A[b] (M x K) * Bt[b]^T
//   A: m-major, k-contiguous (fp32 -> converted in staging, or bf16 direct)
//   Bt: n-major, k-contiguous bf16  (i.e. B transposed)
//   C: fp32 or bf16, m-major
// blockIdx = (mtile, ntile, batch)
// ---------------------------------------------------------------------------
template<int BN, bool AF32, bool CBF16>
__global__ __launch_bounds__(256, 2) void gemm_tile(
    const void* __restrict__ Av, const u16* __restrict__ Bt, void* __restrict__ Cv,
    int K, int lda, int ldb, int ldc,
    long long sA, long long sB, long long sC)
{
  constexpr int BM = 128, BK = 32, PAD = BK + 8;   // +8 bf16 pad kills bank conflicts
  __shared__ __align__(16) u16 As[BM * PAD];
  __shared__ __align__(16) u16 Bs[BN * PAD];
  const int tid  = threadIdx.x;
  const int w    = tid >> 6;
  const int lane = tid & 63;
  const int l15  = lane & 15, quad = lane >> 4;
  const int m0 = blockIdx.x * BM, n0 = blockIdx.y * BN;
  const int bz = blockIdx.z;

  const u16* Bp = Bt + (size_t)sB * bz;

  f32x4 acc[2][BN / 16];
#pragma unroll
  for (int i = 0; i < 2; i++)
#pragma unroll
    for (int j = 0; j < BN / 16; j++)
#pragma unroll
      for (int r = 0; r < 4; r++) acc[i][j][r] = 0.f;

  for (int k0 = 0; k0 < K; k0 += BK) {
    __syncthreads();
    if constexpr (AF32) {
      const float* Af = (const float*)Av + (size_t)sA * bz;
      const int r = tid >> 3, c = (tid & 7) << 2;
#pragma unroll
      for (int rr = 0; rr < 4; rr++) {
        const int row = rr * 32 + r;
        const float4 v = *(const float4*)(Af + (size_t)(m0 + row) * lda + k0 + c);
        uint2 p;
        p.x = f2bf(v.x) | (f2bf(v.y) << 16);
        p.y = f2bf(v.z) | (f2bf(v.w) << 16);
        *(uint2*)(As + row * PAD + c) = p;
      }
    } else {
      const u16* Ah = (const u16*)Av + (size_t)sA * bz;
      const int r = tid >> 2, c = (tid & 3) << 3;
#pragma unroll
      for (int rr = 0; rr < 2; rr++) {
        const int row = rr * 64 + r;
        *(uint4*)(As + row * PAD + c) =
            *(const uint4*)(Ah + (size_t)(m0 + row) * lda + k0 + c);
      }
    }
    {
      const int r = tid >> 2, c = (tid & 3) << 3;
#pragma unroll
      for (int p = 0; p < BN / 64; p++) {
        const int n = p * 64 + r;
        *(uint4*)(Bs + n * PAD + c) =
            *(const uint4*)(Bp + (size_t)(n0 + n) * ldb + k0 + c);
      }
    }
    __syncthreads();
    const bf16x8 a0 = *(const bf16x8*)(As + (w * 32 + l15) * PAD + quad * 8);
    const bf16x8 a1 = *(const bf16x8*)(As + (w * 32 + 16 + l15) * PAD + quad * 8);
#pragma unroll
    for (int nt = 0; nt < BN / 16; nt++) {
      const bf16x8 bv = *(const bf16x8*)(Bs + (nt * 16 + l15) * PAD + quad * 8);
      acc[0][nt] = __builtin_amdgcn_mfma_f32_16x16x32_bf16(a0, bv, acc[0][nt], 0, 0, 0);
      acc[1][nt] = __builtin_amdgcn_mfma_f32_16x16x32_bf16(a1, bv, acc[1][nt], 0, 0, 0);
    }
  }

  // epilogue: C/D layout col = lane&15, row = quad*4 + reg  [m89-verified]
#pragma unroll
  for (int mt = 0; mt < 2; mt++)
#pragma unroll
    for (int nt = 0; nt < BN / 16; nt++)
#pragma unroll
      for (int rg = 0; rg < 4; rg++) {
        const size_t row = (size_t)m0 + w * 32 + mt * 16 + quad * 4 + rg;
        const size_t col = (size_t)n0 + nt * 16 + l15;
        if constexpr (CBF16)
          *((u16*)Cv + (size_t)sC * bz + row * ldc + col) = (u16)f2bf(acc[mt][nt][rg]);
        else
          *((float*)Cv + (size_t)sC * bz + row * ldc + col) = acc[mt][nt][rg];
      }
}

// ---------------------------------------------------------------------------
// Wave-per-row LayerNorm(+bias)+ReLU over 256 features.
// MEAN=false: store bf16 H.   MEAN=true: block-partial node-mean -> atomicAdd.
// ---------------------------------------------------------------------------
template<bool MEAN>
__global__ __launch_bounds__(256) void ln_relu_kernel(
    const float* __restrict__ U, const float* __restrict__ bias,
    const float* __restrict__ gam, const float* __restrict__ bet,
    u16* __restrict__ H, float* __restrict__ gcn)
{
  const int wv = threadIdx.x >> 6, lane = threadIdx.x & 63;
  const size_t row = (size_t)blockIdx.x * 4 + wv;
  const int c = lane * 4;
  float4 v = *(const float4*)(U + row * 256 + c);
  const float4 bv = *(const float4*)(bias + c);
  v.x += bv.x; v.y += bv.y; v.z += bv.z; v.w += bv.w;
  float s = v.x + v.y + v.z + v.w;
#pragma unroll
  for (int off = 32; off >= 1; off >>= 1) s += __shfl_xor(s, off);
  const float mu = s * (1.f / 256.f);
  const float dx = v.x - mu, dy = v.y - mu, dz = v.z - mu, dw = v.w - mu;
  float q = dx * dx + dy * dy + dz * dz + dw * dw;
#pragma unroll
  for (int off = 32; off >= 1; off >>= 1) q += __shfl_xor(q, off);
  const float inv = rsqrtf(q * (1.f / 256.f) + 1e-5f);
  const float4 gv = *(const float4*)(gam + c);
  const float4 ev = *(const float4*)(bet + c);
  const float y0 = fmaxf(dx * inv * gv.x + ev.x, 0.f);
  const float y1 = fmaxf(dy * inv * gv.y + ev.y, 0.f);
  const float y2 = fmaxf(dz * inv * gv.z + ev.z, 0.f);
  const float y3 = fmaxf(dw * inv * gv.w + ev.w, 0.f);
  if constexpr (!MEAN) {
    uint2 p;
    p.x = f2bf(y0) | (f2bf(y1) << 16);
    p.y = f2bf(y2) | (f2bf(y3) << 16);
    *(uint2*)(H + row * 256 + c) = p;
  } else {
    __shared__ float ps[4][256];
    ps[wv][c + 0] = y0; ps[wv][c + 1] = y1; ps[wv][c + 2] = y2; ps[wv][c + 3] = y3;
    __syncthreads();
    const int t = threadIdx.x;
    const float s4 = ps[0][t] + ps[1][t] + ps[2][t] + ps[3][t];
    const int b = blockIdx.x >> 9;  // 512 blocks (2048 rows) per batch
    atomicAdd(gcn + b * 256 + t, s4);
  }
}

// X (B,2048,64) fp32 -> XT (B,64,2048) bf16 via LDS transpose
__global__ __launch_bounds__(256) void xt_kernel(const float* __restrict__ X,
                                                 u16* __restrict__ XTp)
{
  __shared__ float tile[64][65];
  const int b = blockIdx.y, n0 = blockIdx.x * 64;
  const int t = threadIdx.x;
  {
    const int r = t >> 2, c4 = t & 3;
    const float* xp = X + ((size_t)b * 2048 + n0 + r) * 64;
#pragma unroll
    for (int i = 0; i < 4; i++) {
      const float4 v = *(const float4*)(xp + (c4 + i * 4) * 4);
      tile[r][(c4 + i * 4) * 4 + 0] = v.x;
      tile[r][(c4 + i * 4) * 4 + 1] = v.y;
      tile[r][(c4 + i * 4) * 4 + 2] = v.z;
      tile[r][(c4 + i * 4) * 4 + 3] = v.w;
    }
  }
  __syncthreads();
  {
    const int f = t >> 2, ch = t & 3;
    unsigned pk[8];
#pragma unroll
    for (int i = 0; i < 8; i++)
      pk[i] = f2bf(tile[ch * 16 + 2 * i][f]) | (f2bf(tile[ch * 16 + 2 * i + 1][f]) << 16);
    uint4* dst = (uint4*)(XTp + ((size_t)b * 64 + f) * 2048 + n0 + ch * 16);
    dst[0] = make_uint4(pk[0], pk[1], pk[2], pk[3]);
    dst[1] = make_uint4(pk[4], pk[5], pk[6], pk[7]);
  }
}

// small matrix transpose + bf16 convert: out[c*rows + r] = in[r*cols + c]
__global__ __launch_bounds__(256) void transpose_bf16(const float* __restrict__ in,
                                                      u16* __restrict__ outp,
                                                      int rows, int cols)
{
  const int n = rows * cols;
  const int o = blockIdx.x * 256 + threadIdx.x;
  if (o < n) {
    const int c = o / rows, r = o - c * rows;
    outp[o] = (u16)f2bf(in[r * cols + c]);
  }
}

__global__ void zero_kernel(float* p, int n) {
  const int i = blockIdx.x * 256 + threadIdx.x;
  if (i < n) p[i] = 0.f;
}

// fused readout: fused=[gcn/2048, gv]; pred_y=fused@Ws+bs; pred_arr=fused@Wa+ba
__global__ __launch_bounds__(128) void final_kernel(
    const float* __restrict__ gcn, const float* __restrict__ gv,
    const float* __restrict__ Ws, const float* __restrict__ bs,
    const float* __restrict__ Wa, const float* __restrict__ ba,
    float* __restrict__ out)
{
  const int b = blockIdx.x, t = threadIdx.x;
  __shared__ float fused[274];
  fused[t] = gcn[b * 256 + t] * (1.f / 2048.f);
  fused[128 + t] = gcn[b * 256 + 128 + t] * (1.f / 2048.f);
  if (t < 18) fused[256 + t] = gv[b * 18 + t];
  __syncthreads();
  float acc = ba[t];
  for (int i = 0; i < 274; i++) acc = fmaf(fused[i], Wa[i * 128 + t], acc);
  out[16 + b * 128 + t] = acc;
  if (t < 64) {
    float p = 0.f;
    for (int i = t; i < 274; i += 64) p += fused[i] * Ws[i];
#pragma unroll
    for (int off = 32; off >= 1; off >>= 1) p += __shfl_xor(p, off);
    if (t == 0) out[b] = p + bs[0];
  }
}

extern "C" void kernel_launch(void* const* d_in, const int* in_sizes, int n_in,
                              void* d_out, int out_size, void* d_ws, size_t ws_size,
                              hipStream_t stream)
{
  const float* A   = (const float*)d_in[0];   // (16,2048,2048)
  const float* X   = (const float*)d_in[1];   // (16,2048,64)
  const float* GV  = (const float*)d_in[2];   // (16,18)
  const float* W1  = (const float*)d_in[3];   // (64,256)
  const float* b1  = (const float*)d_in[4];
  const float* g1  = (const float*)d_in[5];
  const float* be1 = (const float*)d_in[6];
  const float* W2  = (const float*)d_in[7];   // (256,256)
  const float* b2  = (const float*)d_in[8];
  const float* g2  = (const float*)d_in[9];
  const float* be2 = (const float*)d_in[10];
  const float* Ws  = (const float*)d_in[11];  // (274,1)
  const float* bs  = (const float*)d_in[12];
  const float* Wa  = (const float*)d_in[13];  // (274,128)
  const float* ba  = (const float*)d_in[14];
  float* out = (float*)d_out;

  char* ws = (char*)d_ws;
  u16*   XT  = (u16*)(ws + 0);          //  4,194,304 B  (B,64,2048) bf16
  u16*   W1T = (u16*)(ws + 4194304);    //     32,768 B  (256,64) bf16
  u16*   W2T = (u16*)(ws + 4227072);    //    131,072 B  (256,256) bf16
  u16*   T1  = (u16*)(ws + 4358144);    //  4,194,304 B  (B*2048,64) bf16  = A@X
  u16*   H1  = (u16*)(ws + 8552448);    // 16,777,216 B  (B*2048,256) bf16
  u16*   HWT = (u16*)(ws + 25329664);   // 16,777,216 B  (B,256,2048) bf16 = (H1@W2)^T
  float* U1  = (float*)(ws + 42106880); // 33,554,432 B  fp32, aliased:
  float* T2  = U1;                      //   U1 = T1@W1 (dead after ln1), T2 = A@HW
  float* GCN = (float*)(ws + 75661312); //     16,384 B  (16,256) fp32
  // total 75,677,696 B
  (void)ws_size; (void)in_sizes; (void)n_in; (void)out_size;

  zero_kernel<<<16, 256, 0, stream>>>(GCN, 4096);
  transpose_bf16<<<64, 256, 0, stream>>>(W1, W1T, 64, 256);
  transpose_bf16<<<256, 256, 0, stream>>>(W2, W2T, 256, 256);
  xt_kernel<<<dim3(32, 16), 256, 0, stream>>>(X, XT);

  // T1 = A @ X            (M=2048, N=64, K=2048 per batch)
  gemm_tile<64, true, true><<<dim3(16, 1, 16), 256, 0, stream>>>(
      A, XT, T1, 2048, 2048, 2048, 64, 4194304LL, 131072LL, 131072LL);
  // U1 = T1 @ W1          (M=32768 flat, N=256, K=64)
  gemm_tile<128, false, false><<<dim3(256, 2, 1), 256, 0, stream>>>(
      T1, W1T, U1, 64, 64, 64, 256, 0LL, 0LL, 0LL);
  // H1 = relu(LN(U1 + b1))
  ln_relu_kernel<false><<<8192, 256, 0, stream>>>(U1, b1, g1, be1, H1, nullptr);
  // HWT = W2^T @ H1^T  -> (H1@W2)^T   (M=256, N=2048, K=256 per batch)
  gemm_tile<128, false, true><<<dim3(2, 16, 16), 256, 0, stream>>>(
      W2T, H1, HWT, 256, 256, 256, 2048, 0LL, 524288LL, 524288LL);
  // T2 = A @ (H1@W2)      (M=2048, N=256, K=2048 per batch)
  gemm_tile<128, true, false><<<dim3(16, 2, 16), 256, 0, stream>>>(
      A, HWT, T2, 2048, 2048, 2048, 256, 4194304LL, 524288LL, 524288LL);
  // gcn += sum_nodes relu(LN(T2 + b2))
  ln_relu_kernel<true><<<8192, 256, 0, stream>>>(T2, b2, g2, be2, nullptr, GCN);
  // heads
  final_kernel<<<16, 128, 0, stream>>>(GCN, GV, Ws, bs, Wa, ba, out);
}

// Round 2
// 654.367 us; speedup vs baseline: 1.1268x; 1.1268x over previous
//
#include <hip/hip_runtime.h>

typedef unsigned short u16;
typedef __attribute__((ext_vector_type(8))) short bf16x8;
typedef __attribute__((ext_vector_type(4))) float f32x4;

__device__ __forceinline__ unsigned f2bf(float f) {
  unsigned u = __float_as_uint(f);
  return (u + 0x7fffu + ((u >> 16) & 1u)) >> 16;  // RNE fp32 -> bf16 bits
}

// async global->LDS, 16B per lane. LDS dest is wave-uniform base + lane*16,
// so the LDS tile layout must be unpadded and match lane order exactly.
__device__ __forceinline__ void async16(const u16* g, u16* l) {
  __builtin_amdgcn_global_load_lds(
      (const __attribute__((address_space(1))) void*)g,
      (__attribute__((address_space(3))) void*)l, 16, 0, 0);
}

// ---------------------------------------------------------------------------
// Small tiled MFMA GEMM (round-0, verified): C = A * Bt^T, m-major C.
// ---------------------------------------------------------------------------
template<int BN, bool AF32, bool CBF16>
__global__ __launch_bounds__(256, 2) void gemm_tile(
    const void* __restrict__ Av, const u16* __restrict__ Bt, void* __restrict__ Cv,
    int K, int lda, int ldb, int ldc,
    long long sA, long long sB, long long sC)
{
  constexpr int BM = 128, BK = 32, PAD = BK + 8;
  __shared__ __align__(16) u16 As[BM * PAD];
  __shared__ __align__(16) u16 Bs[BN * PAD];
  const int tid  = threadIdx.x;
  const int w    = tid >> 6;
  const int lane = tid & 63;
  const int l15  = lane & 15, quad = lane >> 4;
  const int m0 = blockIdx.x * BM, n0 = blockIdx.y * BN;
  const int bz = blockIdx.z;

  const u16* Bp = Bt + (size_t)sB * bz;

  f32x4 acc[2][BN / 16];
#pragma unroll
  for (int i = 0; i < 2; i++)
#pragma unroll
    for (int j = 0; j < BN / 16; j++)
#pragma unroll
      for (int r = 0; r < 4; r++) acc[i][j][r] = 0.f;

  for (int k0 = 0; k0 < K; k0 += BK) {
    __syncthreads();
    if constexpr (AF32) {
      const float* Af = (const float*)Av + (size_t)sA * bz;
      const int r = tid >> 3, c = (tid & 7) << 2;
#pragma unroll
      for (int rr = 0; rr < 4; rr++) {
        const int row = rr * 32 + r;
        const float4 v = *(const float4*)(Af + (size_t)(m0 + row) * lda + k0 + c);
        uint2 p;
        p.x = f2bf(v.x) | (f2bf(v.y) << 16);
        p.y = f2bf(v.z) | (f2bf(v.w) << 16);
        *(uint2*)(As + row * PAD + c) = p;
      }
    } else {
      const u16* Ah = (const u16*)Av + (size_t)sA * bz;
      const int r = tid >> 2, c = (tid & 3) << 3;
#pragma unroll
      for (int rr = 0; rr < 2; rr++) {
        const int row = rr * 64 + r;
        *(uint4*)(As + row * PAD + c) =
            *(const uint4*)(Ah + (size_t)(m0 + row) * lda + k0 + c);
      }
    }
    {
      const int r = tid >> 2, c = (tid & 3) << 3;
#pragma unroll
      for (int p = 0; p < BN / 64; p++) {
        const int n = p * 64 + r;
        *(uint4*)(Bs + n * PAD + c) =
            *(const uint4*)(Bp + (size_t)(n0 + n) * ldb + k0 + c);
      }
    }
    __syncthreads();
    const bf16x8 a0 = *(const bf16x8*)(As + (w * 32 + l15) * PAD + quad * 8);
    const bf16x8 a1 = *(const bf16x8*)(As + (w * 32 + 16 + l15) * PAD + quad * 8);
#pragma unroll
    for (int nt = 0; nt < BN / 16; nt++) {
      const bf16x8 bv = *(const bf16x8*)(Bs + (nt * 16 + l15) * PAD + quad * 8);
      acc[0][nt] = __builtin_amdgcn_mfma_f32_16x16x32_bf16(a0, bv, acc[0][nt], 0, 0, 0);
      acc[1][nt] = __builtin_amdgcn_mfma_f32_16x16x32_bf16(a1, bv, acc[1][nt], 0, 0, 0);
    }
  }
#pragma unroll
  for (int mt = 0; mt < 2; mt++)
#pragma unroll
    for (int nt = 0; nt < BN / 16; nt++)
#pragma unroll
      for (int rg = 0; rg < 4; rg++) {
        const size_t row = (size_t)m0 + w * 32 + mt * 16 + quad * 4 + rg;
        const size_t col = (size_t)n0 + nt * 16 + l15;
        if constexpr (CBF16)
          *((u16*)Cv + (size_t)sC * bz + row * ldc + col) = (u16)f2bf(acc[mt][nt][rg]);
        else
          *((float*)Cv + (size_t)sC * bz + row * ldc + col) = acc[mt][nt][rg];
      }
}

// ---------------------------------------------------------------------------
// Fused GCN layer gemm: C[b] = A[b](2048x2048) @ Bt[b]^T (Bt: 256 x 2048),
// epilogue: +bias, LayerNorm over 256 features, ReLU.
//   MEAN=false: store H bf16 (node-major).  MEAN=true: column sums -> gcn.
// BM=64, BN=256 (full feature dim per block), BK=64. grid=(32 mtiles, 16 b).
// ---------------------------------------------------------------------------
template<bool AF32, bool MEAN>
__global__ __launch_bounds__(256, 2) void gcn_gemm(
    const void* __restrict__ Av, const u16* __restrict__ Bt,
    const float* __restrict__ bias, const float* __restrict__ gam,
    const float* __restrict__ bet, u16* __restrict__ H, float* __restrict__ gcn)
{
  constexpr int BK = 64;
  __shared__ __align__(16) u16 As[64 * BK];    //  8 KB, unpadded (async16)
  __shared__ __align__(16) u16 Bs[256 * BK];   // 32 KB, unpadded (async16)
  __shared__ float colsum[256];
  const int tid = threadIdx.x;
  const int w = tid >> 6, lane = tid & 63, l15 = lane & 15, quad = lane >> 4;
  const int m0 = blockIdx.x * 64;
  const int bz = blockIdx.y;

  f32x4 acc[16];
#pragma unroll
  for (int nt = 0; nt < 16; nt++)
#pragma unroll
    for (int r = 0; r < 4; r++) acc[nt][r] = 0.f;

  const int sr = tid >> 3, sc = (tid & 7) << 3;  // staging: row-in-chunk, k-col
  const u16* Bg = Bt + (size_t)bz * 524288 + (size_t)sr * 2048 + sc;
  u16* lA = As + tid * 8;
  u16* lB = Bs + tid * 8;
  const float* Af = nullptr;
  const u16* Ag = nullptr;
  if constexpr (AF32)
    Af = (const float*)Av + (size_t)bz * 4194304 + (size_t)(m0 + sr) * 2048 + sc;
  else
    Ag = (const u16*)Av + (size_t)bz * 4194304 + (size_t)(m0 + sr) * 2048 + sc;

  for (int k0 = 0; k0 < 2048; k0 += BK) {
    __syncthreads();
    if constexpr (AF32) {
#pragma unroll
      for (int q = 0; q < 2; q++) {
        const float* p = Af + (size_t)q * 32 * 2048 + k0;
        const float4 v0 = *(const float4*)p;
        const float4 v1 = *(const float4*)(p + 4);
        uint4 r;
        r.x = f2bf(v0.x) | (f2bf(v0.y) << 16);
        r.y = f2bf(v0.z) | (f2bf(v0.w) << 16);
        r.z = f2bf(v1.x) | (f2bf(v1.y) << 16);
        r.w = f2bf(v1.z) | (f2bf(v1.w) << 16);
        *(uint4*)(lA + q * 2048) = r;
      }
    } else {
#pragma unroll
      for (int q = 0; q < 2; q++)
        async16(Ag + (size_t)q * 32 * 2048 + k0, lA + q * 2048);
    }
#pragma unroll
    for (int p = 0; p < 8; p++)
      async16(Bg + (size_t)p * 65536 + k0, lB + p * 2048);
    __syncthreads();
#pragma unroll
    for (int kk = 0; kk < 2; kk++) {
      const bf16x8 a = *(const bf16x8*)(As + (w * 16 + l15) * BK + kk * 32 + quad * 8);
#pragma unroll
      for (int nt = 0; nt < 16; nt++) {
        const bf16x8 b = *(const bf16x8*)(Bs + (nt * 16 + l15) * BK + kk * 32 + quad * 8);
        acc[nt] = __builtin_amdgcn_mfma_f32_16x16x32_bf16(a, b, acc[nt], 0, 0, 0);
      }
    }
  }

  // ---- epilogue: +bias, LN over the 256 cols of each row, ReLU ----
  // C/D layout: col = nt*16 + l15, row (within wave) = quad*4 + rg.
  float s[4] = {0.f, 0.f, 0.f, 0.f};
#pragma unroll
  for (int nt = 0; nt < 16; nt++) {
    const float bv = bias[nt * 16 + l15];
#pragma unroll
    for (int rg = 0; rg < 4; rg++) { acc[nt][rg] += bv; s[rg] += acc[nt][rg]; }
  }
#pragma unroll
  for (int off = 8; off >= 1; off >>= 1)
#pragma unroll
    for (int rg = 0; rg < 4; rg++) s[rg] += __shfl_xor(s[rg], off);
  float mu[4], qv[4] = {0.f, 0.f, 0.f, 0.f};
#pragma unroll
  for (int rg = 0; rg < 4; rg++) mu[rg] = s[rg] * (1.f / 256.f);
#pragma unroll
  for (int nt = 0; nt < 16; nt++)
#pragma unroll
    for (int rg = 0; rg < 4; rg++) {
      const float d = acc[nt][rg] - mu[rg];
      qv[rg] += d * d;
    }
#pragma unroll
  for (int off = 8; off >= 1; off >>= 1)
#pragma unroll
    for (int rg = 0; rg < 4; rg++) qv[rg] += __shfl_xor(qv[rg], off);
  float inv[4];
#pragma unroll
  for (int rg = 0; rg < 4; rg++) inv[rg] = rsqrtf(qv[rg] * (1.f / 256.f) + 1e-5f);

  if constexpr (!MEAN) {
#pragma unroll
    for (int nt = 0; nt < 16; nt++) {
      const float gv = gam[nt * 16 + l15], ev = bet[nt * 16 + l15];
#pragma unroll
      for (int rg = 0; rg < 4; rg++) {
        const float y = fmaxf((acc[nt][rg] - mu[rg]) * inv[rg] * gv + ev, 0.f);
        const size_t row = (size_t)bz * 2048 + m0 + w * 16 + quad * 4 + rg;
        H[row * 256 + nt * 16 + l15] = (u16)f2bf(y);
      }
    }
  } else {
    colsum[tid] = 0.f;
    __syncthreads();
#pragma unroll
    for (int nt = 0; nt < 16; nt++) {
      const float gv = gam[nt * 16 + l15], ev = bet[nt * 16 + l15];
      float p = 0.f;
#pragma unroll
      for (int rg = 0; rg < 4; rg++)
        p += fmaxf((acc[nt][rg] - mu[rg]) * inv[rg] * gv + ev, 0.f);
      p += __shfl_xor(p, 16);
      p += __shfl_xor(p, 32);          // reduce over the 4 quads (16 rows)
      if (quad == 0) atomicAdd(&colsum[nt * 16 + l15], p);
    }
    __syncthreads();
    atomicAdd(gcn + bz * 256 + tid, colsum[tid]);
  }
}

// fp32 -> bf16, 8 elems/thread (32B read, 16B write)
__global__ __launch_bounds__(256) void convert_bf16(const float* __restrict__ in,
                                                    u16* __restrict__ out, long long n8)
{
  const long long i = (long long)blockIdx.x * 256 + threadIdx.x;
  if (i >= n8) return;
  const float4 a = ((const float4*)in)[2 * i];
  const float4 b = ((const float4*)in)[2 * i + 1];
  uint4 r;
  r.x = f2bf(a.x) | (f2bf(a.y) << 16);
  r.y = f2bf(a.z) | (f2bf(a.w) << 16);
  r.z = f2bf(b.x) | (f2bf(b.y) << 16);
  r.w = f2bf(b.z) | (f2bf(b.w) << 16);
  ((uint4*)out)[i] = r;
}

// small matrix transpose + bf16 convert: out[c*rows + r] = in[r*cols + c]
__global__ __launch_bounds__(256) void transpose_bf16(const float* __restrict__ in,
                                                      u16* __restrict__ outp,
                                                      int rows, int cols)
{
  const int n = rows * cols;
  const int o = blockIdx.x * 256 + threadIdx.x;
  if (o < n) {
    const int c = o / rows, r = o - c * rows;
    outp[o] = (u16)f2bf(in[r * cols + c]);
  }
}

__global__ void zero_kernel(float* p, int n) {
  const int i = blockIdx.x * 256 + threadIdx.x;
  if (i < n) p[i] = 0.f;
}

// fused readout: fused=[gcn/2048, gv]; pred_y=fused@Ws+bs; pred_arr=fused@Wa+ba
__global__ __launch_bounds__(128) void final_kernel(
    const float* __restrict__ gcn, const float* __restrict__ gv,
    const float* __restrict__ Ws, const float* __restrict__ bs,
    const float* __restrict__ Wa, const float* __restrict__ ba,
    float* __restrict__ out)
{
  const int b = blockIdx.x, t = threadIdx.x;
  __shared__ float fused[274];
  fused[t] = gcn[b * 256 + t] * (1.f / 2048.f);
  fused[128 + t] = gcn[b * 256 + 128 + t] * (1.f / 2048.f);
  if (t < 18) fused[256 + t] = gv[b * 18 + t];
  __syncthreads();
  float acc = ba[t];
  for (int i = 0; i < 274; i++) acc = fmaf(fused[i], Wa[i * 128 + t], acc);
  out[16 + b * 128 + t] = acc;
  if (t < 64) {
    float p = 0.f;
    for (int i = t; i < 274; i += 64) p += fused[i] * Ws[i];
#pragma unroll
    for (int off = 32; off >= 1; off >>= 1) p += __shfl_xor(p, off);
    if (t == 0) out[b] = p + bs[0];
  }
}

extern "C" void kernel_launch(void* const* d_in, const int* in_sizes, int n_in,
                              void* d_out, int out_size, void* d_ws, size_t ws_size,
                              hipStream_t stream)
{
  const float* A   = (const float*)d_in[0];   // (16,2048,2048)
  const float* X   = (const float*)d_in[1];   // (16,2048,64)
  const float* GV  = (const float*)d_in[2];   // (16,18)
  const float* W1  = (const float*)d_in[3];   // (64,256)
  const float* b1  = (const float*)d_in[4];
  const float* g1  = (const float*)d_in[5];
  const float* be1 = (const float*)d_in[6];
  const float* W2  = (const float*)d_in[7];   // (256,256)
  const float* b2  = (const float*)d_in[8];
  const float* g2  = (const float*)d_in[9];
  const float* be2 = (const float*)d_in[10];
  const float* Ws  = (const float*)d_in[11];  // (274,1)
  const float* bs  = (const float*)d_in[12];
  const float* Wa  = (const float*)d_in[13];  // (274,128)
  const float* ba  = (const float*)d_in[14];
  float* out = (float*)d_out;
  (void)in_sizes; (void)n_in; (void)out_size;

  // Workspace: big path converts A to bf16 once (needs ~189 MB); fallback
  // converts A fp32->bf16 on the fly inside the big gemms (needs ~55 MB).
  const bool big = ws_size >= (size_t)188923904;
  char* ws   = (char*)d_ws;
  u16*  Abf  = (u16*)ws;                              // 134,217,728 B (big only)
  char* base = big ? ws + 134217728 : ws;
  u16*   Xbf = (u16*)(base + 0);                      //  4,194,304 B (B,2048,64) bf16
  u16*   W1T = (u16*)(base + 4194304);                //     32,768 B (256,64)
  u16*   W2T = (u16*)(base + 4227072);                //    131,072 B (256,256)
  u16*   XWT = (u16*)(base + 4358144);                // 16,777,216 B (B,256,2048) = (X@W1)^T
  u16*   H1  = (u16*)(base + 21135360);               // 16,777,216 B (B,2048,256)
  u16*   HWT = (u16*)(base + 37912576);               // 16,777,216 B (B,256,2048) = (H1@W2)^T
  float* GCN = (float*)(base + 54689792);             //     16,384 B (16,256)

  zero_kernel<<<16, 256, 0, stream>>>(GCN, 4096);
  convert_bf16<<<1024, 256, 0, stream>>>(X, Xbf, 262144LL);
  transpose_bf16<<<64, 256, 0, stream>>>(W1, W1T, 64, 256);
  transpose_bf16<<<256, 256, 0, stream>>>(W2, W2T, 256, 256);
  if (big) convert_bf16<<<32768, 256, 0, stream>>>(A, Abf, 8388608LL);

  // XWT = (X@W1)^T : C[f][node] = sum_k W1T[f][k] * Xbf[node][k]
  gemm_tile<128, false, true><<<dim3(2, 16, 16), 256, 0, stream>>>(
      W1T, Xbf, XWT, 64, 64, 64, 2048, 0LL, 131072LL, 524288LL);

  // H1 = relu(LN(A @ (X@W1) + b1))
  if (big)
    gcn_gemm<false, false><<<dim3(32, 16), 256, 0, stream>>>(
        Abf, XWT, b1, g1, be1, H1, nullptr);
  else
    gcn_gemm<true, false><<<dim3(32, 16), 256, 0, stream>>>(
        A, XWT, b1, g1, be1, H1, nullptr);

  // HWT = (H1@W2)^T : C[f][node] = sum_k W2T[f][k] * H1[node][k]
  gemm_tile<128, false, true><<<dim3(2, 16, 16), 256, 0, stream>>>(
      W2T, H1, HWT, 256, 256, 256, 2048, 0LL, 524288LL, 524288LL);

  // GCN[b][c] = sum_nodes relu(LN(A @ (H1@W2) + b2))
  if (big)
    gcn_gemm<false, true><<<dim3(32, 16), 256, 0, stream>>>(
        Abf, HWT, b2, g2, be2, nullptr, GCN);
  else
    gcn_gemm<true, true><<<dim3(32, 16), 256, 0, stream>>>(
        A, HWT, b2, g2, be2, nullptr, GCN);

  final_kernel<<<16, 128, 0, stream>>>(GCN, GV, Ws, bs, Wa, ba, out);
}